// Round 2
// baseline (598.374 us; speedup 1.0000x reference)
//
#include <hip/hip_runtime.h>
#include <hip/hip_bf16.h>
#include <hip/hip_cooperative_groups.h>

namespace cg = cooperative_groups;

typedef __bf16 bf16;
typedef __bf16 bf16x4 __attribute__((ext_vector_type(4)));
typedef __bf16 bf16x8 __attribute__((ext_vector_type(8)));
typedef float f32x4 __attribute__((ext_vector_type(4)));

#define HID 4096
#define NQH 32
#define NKVH 8
#define HD 128
#define MAXLEN 8192
#define SCALE 0.08838834764831845f
#define NEGBIG (-30000.0f)

#define KS 8          // K splits per GEMM N-tile
#define KPB 512       // K elements per GEMM unit
#define WSTR 520      // LDS row stride for W tile
#define ACH 64        // keys per past chunk
#define NCH 65        // 64 past chunks + 1 new chunk
#define NBLK 520      // fused grid size == attn parallelism

__device__ __forceinline__ f32x4 mfma16(bf16x8 a, bf16x8 b, f32x4 c) {
  return __builtin_amdgcn_mfma_f32_16x16x32_bf16(a, b, c, 0, 0, 0);
}

__device__ __forceinline__ bf16x8 load8f(const float* p) {
  const f32x4* q = (const f32x4*)p;
  f32x4 a = q[0], b = q[1];
  bf16x8 r;
  r[0] = (bf16)a[0]; r[1] = (bf16)a[1]; r[2] = (bf16)a[2]; r[3] = (bf16)a[3];
  r[4] = (bf16)b[0]; r[5] = (bf16)b[1]; r[6] = (bf16)b[2]; r[7] = (bf16)b[3];
  return r;
}

__device__ __forceinline__ int fmidx(int k, int m) {
  return ((k >> 3) * 16 + m) * 8 + (k & 7);
}

// ---------------- LDS overlays ----------------
struct LdsGemm { bf16 Wt[16 * WSTR]; float red[4][64][4]; };          // 20.7 KB
struct LdsAttn { bf16 Kt[64 * 136]; bf16 Vt[128 * 72]; bf16 Pl[4 * 16 * 72]; };  // 45.1 KB
struct LdsComb { float m[4]; float l[4]; float a[4][128]; };          // 2.1 KB
union LdsAll { LdsGemm g; LdsAttn at; LdsComb c; };

// ---------------- phase bodies (shared by fused + fallback) ----------------

__device__ __forceinline__ void xprep_one(const float* __restrict__ x,
                                          bf16* __restrict__ xf, int id) {
  int m = id & 15, o = id >> 4;   // 8192 ids: 16 m x 512 octets
  bf16x8 v = load8f(x + (size_t)m * HID + o * 8);
  *(bf16x8*)(xf + (size_t)(o * 16 + m) * 8) = v;
}

// one 16x16 partial tile over one 512-K slice (R0-proven: staged W, no atomics)
template <int NT>
__device__ __forceinline__ void gemm_unit(const bf16* __restrict__ afrag,
                                          const float* __restrict__ w,
                                          float* __restrict__ partial,
                                          int u, int tid, LdsGemm* L) {
  int lane = tid & 63, wv = tid >> 6, l15 = lane & 15, quad = lane >> 4;
  int nt = u % NT, kq = u / NT;

  const float* wb = w + (size_t)(nt * 16) * HID + kq * KPB;
  int r2 = tid >> 7, c4 = tid & 127;
  f32x4 stg[8];
#pragma unroll
  for (int it = 0; it < 8; ++it)
    stg[it] = *(const f32x4*)(wb + (size_t)(it * 2 + r2) * HID + c4 * 4);

  int obase = kq * 64 + wv * 16;
  bf16x8 af[4];
#pragma unroll
  for (int kk = 0; kk < 4; ++kk)
    af[kk] = *(const bf16x8*)(afrag + (size_t)((obase + kk * 4 + quad) * 16 + l15) * 8);

#pragma unroll
  for (int it = 0; it < 8; ++it) {
    bf16x4 t;
    t[0] = (bf16)stg[it][0]; t[1] = (bf16)stg[it][1];
    t[2] = (bf16)stg[it][2]; t[3] = (bf16)stg[it][3];
    *(bf16x4*)(L->Wt + (it * 2 + r2) * WSTR + c4 * 4) = t;
  }
  __syncthreads();

  f32x4 acc = {0.f, 0.f, 0.f, 0.f};
#pragma unroll
  for (int kk = 0; kk < 4; ++kk) {
    bf16x8 b = *(const bf16x8*)(L->Wt + l15 * WSTR + wv * 128 + kk * 32 + quad * 8);
    acc = mfma16(af[kk], b, acc);
  }

  *(f32x4*)(&L->red[wv][lane][0]) = acc;
  __syncthreads();
  if (wv == 0) {
#pragma unroll
    for (int r = 0; r < 4; ++r) {
      float v = L->red[0][lane][r] + L->red[1][lane][r] + L->red[2][lane][r] + L->red[3][lane][r];
      partial[((size_t)(kq * NT + nt) * 16 + (quad * 4 + r)) * 16 + l15] = v;
    }
  }
  // next-unit Wt writes are safe: all Wt reads complete before the red-sync
}

__device__ __forceinline__ float sum_part(const float* __restrict__ p, int NT, int n, int m) {
  float s = 0.f;
#pragma unroll
  for (int q = 0; q < KS; ++q)
    s += p[((size_t)(q * NT + (n >> 4)) * 16 + m) * 16 + (n & 15)];
  return s;
}

__device__ __forceinline__ void finish_one(const float* __restrict__ pq,
                                           bf16* __restrict__ Qf, bf16* __restrict__ Kf,
                                           bf16* __restrict__ Vn, int id) {
  if (id < 32768) {           // Q: 32 heads x 16 m x 64 pairs
    int qh = id >> 10, m = (id >> 6) & 15, j = id & 63;
    float e = sum_part(pq, 384, qh * 128 + j, m);
    float o = sum_part(pq, 384, qh * 128 + 64 + j, m);
    float sn, co;
    __sincosf((float)m * (float)j * (1.0f / 64.0f), &sn, &co);
    Qf[qh * 2048 + fmidx(j, m)] = (bf16)((e * co - o * sn) * SCALE);
    Qf[qh * 2048 + fmidx(j + 64, m)] = (bf16)((e * sn + o * co) * SCALE);
  } else if (id < 40960) {    // K
    int v = id - 32768;
    int kvh = v >> 10, m = (v >> 6) & 15, j = v & 63;
    float e = sum_part(pq, 384, 4096 + kvh * 128 + j, m);
    float o = sum_part(pq, 384, 4096 + kvh * 128 + 64 + j, m);
    float sn, co;
    __sincosf((float)m * (float)j * (1.0f / 64.0f), &sn, &co);
    Kf[kvh * 2048 + fmidx(j, m)] = (bf16)(e * co - o * sn);
    Kf[kvh * 2048 + fmidx(j + 64, m)] = (bf16)(e * sn + o * co);
  } else if (id < 57344) {    // V
    int v = id - 40960;
    int kvh = v >> 11, m = (v >> 7) & 15, d = v & 127;
    Vn[kvh * 2048 + m * 128 + d] = (bf16)sum_part(pq, 384, 5120 + kvh * 128 + d, m);
  }
}

template <bool NEW>
__device__ __forceinline__ void attn_one(int kvh, int c,
                                         const float* __restrict__ ck, const float* __restrict__ cv,
                                         const bf16* __restrict__ Qf, const bf16* __restrict__ Kf,
                                         const bf16* __restrict__ Vn,
                                         bf16* __restrict__ Opart, float* __restrict__ ml,
                                         LdsAttn* L) {
  int tid = threadIdx.x, lane = tid & 63, wv = tid >> 6;
  int l15 = lane & 15, quad = lane >> 4;
  int qh = kvh * 4 + wv;
  int cs = c * ACH;
  bf16* Kt = L->Kt; bf16* Vt = L->Vt; bf16* Pl = L->Pl;

  if (!NEW) {
    int kr = tid >> 5;
    int kc4 = tid & 31;
    f32x4 kst[8];
#pragma unroll
    for (int it = 0; it < 8; ++it)
      kst[it] = *(const f32x4*)(ck + ((size_t)(kvh * MAXLEN + cs + it * 8 + kr)) * HD + kc4 * 4);
    int key = tid & 63, dg = tid >> 6;
    f32x4 vst[8];
#pragma unroll
    for (int q4 = 0; q4 < 8; ++q4)
      vst[q4] = *(const f32x4*)(cv + ((size_t)(kvh * MAXLEN + cs + key)) * HD + dg * 32 + q4 * 4);
#pragma unroll
    for (int it = 0; it < 8; ++it) {
      bf16x4 t;
      t[0] = (bf16)kst[it][0]; t[1] = (bf16)kst[it][1];
      t[2] = (bf16)kst[it][2]; t[3] = (bf16)kst[it][3];
      *(bf16x4*)(Kt + (it * 8 + kr) * 136 + kc4 * 4) = t;
    }
#pragma unroll
    for (int q4 = 0; q4 < 8; ++q4)
#pragma unroll
      for (int i = 0; i < 4; ++i)
        Vt[(dg * 32 + q4 * 4 + i) * 72 + key] = (bf16)vst[q4][i];
  } else {
    int key = tid >> 4, dg8 = tid & 15;
    bf16x8 v = *(const bf16x8*)(Vn + kvh * 2048 + key * 128 + dg8 * 8);
#pragma unroll
    for (int i = 0; i < 8; ++i) {
      Vt[(dg8 * 8 + i) * 72 + key] = v[i];
      Vt[(dg8 * 8 + i) * 72 + 16 + key] = (bf16)0.f;
    }
  }
  __syncthreads();

  bf16x8 af[4];
#pragma unroll
  for (int kk = 0; kk < 4; ++kk)
    af[kk] = *(const bf16x8*)(Qf + qh * 2048 + ((kk * 4 + quad) * 16 + l15) * 8);

  constexpr int NT = NEW ? 1 : 4;
  f32x4 sc[NT];
  if (!NEW) {
#pragma unroll
    for (int nt = 0; nt < NT; ++nt) {
      f32x4 acc = {0.f, 0.f, 0.f, 0.f};
#pragma unroll
      for (int kk = 0; kk < 4; ++kk) {
        bf16x8 b = *(const bf16x8*)(Kt + (nt * 16 + l15) * 136 + kk * 32 + quad * 8);
        acc = mfma16(af[kk], b, acc);
      }
      sc[nt] = acc;
    }
  } else {
    f32x4 acc = {0.f, 0.f, 0.f, 0.f};
#pragma unroll
    for (int kk = 0; kk < 4; ++kk) {
      bf16x8 b = *(const bf16x8*)(Kf + kvh * 2048 + ((kk * 4 + quad) * 16 + l15) * 8);
      acc = mfma16(af[kk], b, acc);
    }
#pragma unroll
    for (int r = 0; r < 4; ++r)
      if (l15 > quad * 4 + r) acc[r] = NEGBIG;
    sc[0] = acc;
  }

  float mx[4], sm[4];
#pragma unroll
  for (int r = 0; r < 4; ++r) {
    float v = sc[0][r];
#pragma unroll
    for (int nt = 1; nt < NT; ++nt) v = fmaxf(v, sc[nt][r]);
    v = fmaxf(v, __shfl_xor(v, 1));
    v = fmaxf(v, __shfl_xor(v, 2));
    v = fmaxf(v, __shfl_xor(v, 4));
    v = fmaxf(v, __shfl_xor(v, 8));
    mx[r] = v;
  }
#pragma unroll
  for (int nt = 0; nt < NT; ++nt)
#pragma unroll
    for (int r = 0; r < 4; ++r) sc[nt][r] = __expf(sc[nt][r] - mx[r]);
#pragma unroll
  for (int r = 0; r < 4; ++r) {
    float v = 0.f;
#pragma unroll
    for (int nt = 0; nt < NT; ++nt) v += sc[nt][r];
    v += __shfl_xor(v, 1);
    v += __shfl_xor(v, 2);
    v += __shfl_xor(v, 4);
    v += __shfl_xor(v, 8);
    sm[r] = v;
  }

  bf16* Pw = Pl + wv * 16 * 72;
#pragma unroll
  for (int nt = 0; nt < NT; ++nt)
#pragma unroll
    for (int r = 0; r < 4; ++r)
      Pw[(quad * 4 + r) * 72 + nt * 16 + l15] = (bf16)sc[nt][r];
  if (NEW) {
#pragma unroll
    for (int r = 0; r < 4; ++r)
      Pw[(quad * 4 + r) * 72 + 16 + l15] = (bf16)0.f;
  }
  __syncthreads();

  constexpr int KI = NEW ? 1 : 2;
  int rowblk = ((kvh * NCH + c) * 4 + wv) * 16;
  bf16* ob = Opart + (size_t)rowblk * 128;
#pragma unroll
  for (int nt2 = 0; nt2 < 8; ++nt2) {
    f32x4 acc = {0.f, 0.f, 0.f, 0.f};
#pragma unroll
    for (int kk = 0; kk < KI; ++kk) {
      bf16x8 a = *(const bf16x8*)(Pw + l15 * 72 + kk * 32 + quad * 8);
      bf16x8 b = *(const bf16x8*)(Vt + (nt2 * 16 + l15) * 72 + kk * 32 + quad * 8);
      acc = mfma16(a, b, acc);
    }
#pragma unroll
    for (int r = 0; r < 4; ++r)
      ob[(quad * 4 + r) * 128 + nt2 * 16 + l15] = (bf16)acc[r];
  }
  if (l15 == 0) {
#pragma unroll
    for (int r = 0; r < 4; ++r) {
      ml[(size_t)(rowblk + quad * 4 + r) * 2] = mx[r];
      ml[(size_t)(rowblk + quad * 4 + r) * 2 + 1] = sm[r];
    }
  }
}

__device__ __forceinline__ void combine_one(const bf16* __restrict__ Opart,
                                            const float* __restrict__ ml,
                                            bf16* __restrict__ attfm,
                                            int qh, int srow, int tid, LdsComb* L) {
  int lane = tid & 63, wv = tid >> 6;
  int kvh = qh >> 2, lw = qh & 3;
  size_t rowblk0 = ((size_t)(kvh * NCH) * 4 + lw) * 16 + srow;

  float mw = NEGBIG;
  for (int c = wv; c < NCH; c += 4)
    mw = fmaxf(mw, ml[(rowblk0 + (size_t)c * 64) * 2]);

  float a0 = 0.f, a1 = 0.f, Lw = 0.f;
  for (int c = wv; c < NCH; c += 4) {
    const float* mlc = ml + (rowblk0 + (size_t)c * 64) * 2;
    float wc = __expf(mlc[0] - mw);
    Lw += wc * mlc[1];
    const bf16* oc = Opart + (rowblk0 + (size_t)c * 64) * 128;
    a0 += wc * (float)oc[lane];
    a1 += wc * (float)oc[64 + lane];
  }

  if (lane == 0) { L->m[wv] = mw; L->l[wv] = Lw; }
  L->a[wv][lane] = a0;
  L->a[wv][64 + lane] = a1;
  __syncthreads();

  if (wv == 0) {
    float M = fmaxf(fmaxf(L->m[0], L->m[1]), fmaxf(L->m[2], L->m[3]));
    float s0 = __expf(L->m[0] - M), s1 = __expf(L->m[1] - M);
    float s2 = __expf(L->m[2] - M), s3 = __expf(L->m[3] - M);
    float Ls = s0 * L->l[0] + s1 * L->l[1] + s2 * L->l[2] + s3 * L->l[3];
    float inv = 1.f / Ls;
    float A0 = s0 * L->a[0][lane] + s1 * L->a[1][lane] + s2 * L->a[2][lane] + s3 * L->a[3][lane];
    float A1 = s0 * L->a[0][64 + lane] + s1 * L->a[1][64 + lane] +
               s2 * L->a[2][64 + lane] + s3 * L->a[3][64 + lane];
    int k1 = qh * 128 + lane, k2 = k1 + 64;
    attfm[fmidx(k1, srow)] = (bf16)(A0 * inv);
    attfm[fmidx(k2, srow)] = (bf16)(A1 * inv);
  }
}

__device__ __forceinline__ void reduce_one(const float* __restrict__ pp,
                                           float* __restrict__ out, int flat) {
  int m = flat >> 10, n = (flat & 1023) * 4;
  f32x4 s = {0.f, 0.f, 0.f, 0.f};
#pragma unroll
  for (int q = 0; q < KS; ++q)
    s += *(const f32x4*)(pp + ((size_t)(q * 256 + (n >> 4)) * 16 + m) * 16 + (n & 15));
  *(f32x4*)(out + (size_t)m * HID + n) = s;
}

// ---------------- fused cooperative kernel ----------------
__global__ __launch_bounds__(256, 3) void fused_kernel(
    const float* __restrict__ x, const float* __restrict__ w_qkv,
    const float* __restrict__ w_out,
    const float* __restrict__ ck, const float* __restrict__ cv,
    bf16* __restrict__ Xfrag, float* __restrict__ partQ,
    bf16* __restrict__ Qf, bf16* __restrict__ Kf, bf16* __restrict__ Vn,
    bf16* __restrict__ Opart, float* __restrict__ ml,
    bf16* __restrict__ attfm, float* __restrict__ partP,
    float* __restrict__ out) {
  __shared__ __align__(16) LdsAll lds;
  cg::grid_group grid = cg::this_grid();
  int tid = threadIdx.x, b = blockIdx.x;

  // P0: x -> fragment-major bf16 (8192 ids over blocks 0..31)
  {
    int id = b * 256 + tid;
    if (id < 8192) xprep_one(x, Xfrag, id);
  }
  grid.sync();

  // P1: qkv GEMM, 3072 units strided over 520 blocks
  for (int u = b; u < 384 * KS; u += NBLK)
    gemm_unit<384>(Xfrag, w_qkv, partQ, u, tid, &lds.g);
  grid.sync();

  // P2: reduce partials + RoPE (57344 ids over blocks 0..223)
  {
    int id = b * 256 + tid;
    if (id < 57344) finish_one(partQ, Qf, Kf, Vn, id);
  }
  grid.sync();

  // P3: attention partials (exactly 520 blocks)
  {
    int c = b % NCH, kvh = b / NCH;
    if (c == NCH - 1) attn_one<true>(kvh, c, ck, cv, Qf, Kf, Vn, Opart, ml, &lds.at);
    else              attn_one<false>(kvh, c, ck, cv, Qf, Kf, Vn, Opart, ml, &lds.at);
  }
  grid.sync();

  // P4: softmax combine (512 blocks)
  if (b < 512) combine_one(Opart, ml, attfm, b >> 4, b & 15, tid, &lds.c);
  grid.sync();

  // P5: out-proj GEMM, 2048 units
  for (int u = b; u < 256 * KS; u += NBLK)
    gemm_unit<256>(attfm, w_out, partP, u, tid, &lds.g);
  grid.sync();

  // P6: final reduce (16384 ids over blocks 0..63)
  {
    int id = b * 256 + tid;
    if (id < 16384) reduce_one(partP, out, id);
  }
}

// ---------------- fallback wrappers (non-cooperative path) ----------------
__global__ __launch_bounds__(256) void xprep_k(const float* __restrict__ x, bf16* __restrict__ xf) {
  xprep_one(x, xf, blockIdx.x * 256 + threadIdx.x);
}
template <int NT>
__global__ __launch_bounds__(256) void gemm_k(const bf16* __restrict__ a, const float* __restrict__ w,
                                              float* __restrict__ p) {
  __shared__ __align__(16) LdsGemm L;
  gemm_unit<NT>(a, w, p, blockIdx.x, threadIdx.x, &L);
}
__global__ __launch_bounds__(256) void finish_k(const float* __restrict__ pq, bf16* __restrict__ Qf,
                                                bf16* __restrict__ Kf, bf16* __restrict__ Vn) {
  finish_one(pq, Qf, Kf, Vn, blockIdx.x * 256 + threadIdx.x);
}
__global__ __launch_bounds__(256) void attn_k(const float* __restrict__ ck, const float* __restrict__ cv,
                                              const bf16* __restrict__ Qf, const bf16* __restrict__ Kf,
                                              const bf16* __restrict__ Vn, bf16* __restrict__ Opart,
                                              float* __restrict__ ml) {
  __shared__ __align__(16) LdsAttn L;
  int c = blockIdx.x % NCH, kvh = blockIdx.x / NCH;
  if (c == NCH - 1) attn_one<true>(kvh, c, ck, cv, Qf, Kf, Vn, Opart, ml, &L);
  else              attn_one<false>(kvh, c, ck, cv, Qf, Kf, Vn, Opart, ml, &L);
}
__global__ __launch_bounds__(256) void combine_k(const bf16* __restrict__ Opart,
                                                 const float* __restrict__ ml,
                                                 bf16* __restrict__ attfm) {
  __shared__ __align__(16) LdsComb L;
  combine_one(Opart, ml, attfm, (int)blockIdx.x >> 4, (int)blockIdx.x & 15, threadIdx.x, &L);
}
__global__ __launch_bounds__(256) void reduce_k(const float* __restrict__ pp, float* __restrict__ out) {
  reduce_one(pp, out, blockIdx.x * 256 + threadIdx.x);
}

extern "C" void kernel_launch(void* const* d_in, const int* in_sizes, int n_in,
                              void* d_out, int out_size, void* d_ws, size_t ws_size,
                              hipStream_t stream) {
  const float* x       = (const float*)d_in[0];
  const float* w_qkv   = (const float*)d_in[1];
  const float* w_out   = (const float*)d_in[2];
  const float* cache_k = (const float*)d_in[3];
  const float* cache_v = (const float*)d_in[4];
  float* out = (float*)d_out;

  char* p = (char*)d_ws;
  bf16*  Xfrag = (bf16*)p;               p += (size_t)16 * HID * 2;            // 128 KB
  float* partQ = (float*)p;              p += (size_t)KS * 384 * 256 * 4;      // 3 MB
  bf16*  Qf    = (bf16*)p;               p += (size_t)NQH * 2048 * 2;          // 128 KB
  bf16*  Kf    = (bf16*)p;               p += (size_t)NKVH * 2048 * 2;         // 32 KB
  bf16*  Vn    = (bf16*)p;               p += (size_t)NKVH * 2048 * 2;         // 32 KB
  bf16*  Opart = (bf16*)p;               p += (size_t)NKVH * NCH * 4 * 16 * 128 * 2;  // 8.5 MB
  float* ml    = (float*)p;              p += (size_t)NKVH * NCH * 4 * 16 * 2 * 4;    // 266 KB
  bf16*  attfm = (bf16*)p;               p += (size_t)16 * HID * 2;            // 128 KB
  float* partP = (float*)p;              p += (size_t)KS * 256 * 256 * 4;      // 2 MB

  void* args[] = {(void*)&x, (void*)&w_qkv, (void*)&w_out, (void*)&cache_k, (void*)&cache_v,
                  (void*)&Xfrag, (void*)&partQ, (void*)&Qf, (void*)&Kf, (void*)&Vn,
                  (void*)&Opart, (void*)&ml, (void*)&attfm, (void*)&partP, (void*)&out};
  hipError_t e = hipLaunchCooperativeKernel((const void*)fused_kernel, dim3(NBLK), dim3(256),
                                            args, 0, stream);
  if (e != hipSuccess) {
    (void)hipGetLastError();  // clear sticky error; fall back to multi-launch pipeline
    hipLaunchKernelGGL(xprep_k, dim3(32), dim3(256), 0, stream, x, Xfrag);
    hipLaunchKernelGGL((gemm_k<384>), dim3(384 * KS), dim3(256), 0, stream, Xfrag, w_qkv, partQ);
    hipLaunchKernelGGL(finish_k, dim3(224), dim3(256), 0, stream, partQ, Qf, Kf, Vn);
    hipLaunchKernelGGL(attn_k, dim3(NKVH * NCH), dim3(256), 0, stream,
                       cache_k, cache_v, Qf, Kf, Vn, Opart, ml);
    hipLaunchKernelGGL(combine_k, dim3(512), dim3(256), 0, stream, Opart, ml, attfm);
    hipLaunchKernelGGL((gemm_k<256>), dim3(256 * KS), dim3(256), 0, stream, attfm, w_out, partP);
    hipLaunchKernelGGL(reduce_k, dim3(64), dim3(256), 0, stream, partP, out);
  }
}

// Round 4
// 257.550 us; speedup vs baseline: 2.3233x; 2.3233x over previous
//
#include <hip/hip_runtime.h>
#include <hip/hip_bf16.h>

typedef __bf16 bf16;
typedef __bf16 bf16x4 __attribute__((ext_vector_type(4)));
typedef __bf16 bf16x8 __attribute__((ext_vector_type(8)));
typedef float f32x4 __attribute__((ext_vector_type(4)));

#define HID 4096
#define QKVN 6144
#define NQH 32
#define NKVH 8
#define HD 128
#define MAXLEN 8192
#define PAST 4096
#define SQ 16
#define SCALE 0.08838834764831845f
#define NEGBIG (-30000.0f)

// GEMM K-split config
#define KS 8          // K splits (blocks per N-tile)
#define KPB 512       // K elements per block
#define WSTR 520      // LDS row stride (elements) for W tile
// attention chunking
#define ACH 64        // keys per past chunk
#define NCH 65        // 64 past chunks + 1 new chunk

__device__ __forceinline__ f32x4 mfma16(bf16x8 a, bf16x8 b, f32x4 c) {
  return __builtin_amdgcn_mfma_f32_16x16x32_bf16(a, b, c, 0, 0, 0);
}

__device__ __forceinline__ bf16x8 load8f(const float* p) {
  const f32x4* q = (const f32x4*)p;
  f32x4 a = q[0], b = q[1];
  bf16x8 r;
  r[0] = (bf16)a[0]; r[1] = (bf16)a[1]; r[2] = (bf16)a[2]; r[3] = (bf16)a[3];
  r[4] = (bf16)b[0]; r[5] = (bf16)b[1]; r[6] = (bf16)b[2]; r[7] = (bf16)b[3];
  return r;
}

__device__ __forceinline__ int fmidx(int k, int m) {
  return ((k >> 3) * 16 + m) * 8 + (k & 7);
}

// ---------------- Kernel 0: X -> fragment-major bf16 ----------------
__global__ __launch_bounds__(256) void xprep_kernel(const float* __restrict__ x,
                                                    bf16* __restrict__ xf) {
  int id = blockIdx.x * 256 + threadIdx.x;   // 8192 = 16 m * 512 octets
  int m = id & 15, o = id >> 4;
  bf16x8 v = load8f(x + (size_t)m * HID + o * 8);
  *(bf16x8*)(xf + (size_t)(o * 16 + m) * 8) = v;
}

// ---------------- GEMM: C16[m][n] partial = A[16][K] . W[n][K]^T over one K-slice ----------------
template <int NT>
__global__ __launch_bounds__(256) void gemm16_kernel(const bf16* __restrict__ afrag,
                                                     const float* __restrict__ w,
                                                     float* __restrict__ partial) {
  int tid = threadIdx.x, lane = tid & 63, wv = tid >> 6;
  int l15 = lane & 15, quad = lane >> 4;
  int nt = blockIdx.x % NT, kq = blockIdx.x / NT;

  __shared__ __align__(16) bf16 Wt[16 * WSTR];
  __shared__ __align__(16) float red[4][64][4];

  // ---- stage W tile 16 x 512 fp32 -> bf16 LDS, fully coalesced ----
  const float* wb = w + (size_t)(nt * 16) * HID + kq * KPB;
  int r2 = tid >> 7;        // 0..1 (2 rows per iteration)
  int c4 = tid & 127;       // float4 column
  f32x4 stg[8];
#pragma unroll
  for (int it = 0; it < 8; ++it)
    stg[it] = *(const f32x4*)(wb + (size_t)(it * 2 + r2) * HID + c4 * 4);

  // ---- A fragments (coalesced 16B/lane, independent of LDS) ----
  int obase = kq * 64 + wv * 16;   // octet base for this wave (K = kq*512 + wv*128)
  bf16x8 af[4];
#pragma unroll
  for (int kk = 0; kk < 4; ++kk)
    af[kk] = *(const bf16x8*)(afrag + (size_t)((obase + kk * 4 + quad) * 16 + l15) * 8);

#pragma unroll
  for (int it = 0; it < 8; ++it) {
    bf16x4 t;
    t[0] = (bf16)stg[it][0]; t[1] = (bf16)stg[it][1];
    t[2] = (bf16)stg[it][2]; t[3] = (bf16)stg[it][3];
    *(bf16x4*)(Wt + (it * 2 + r2) * WSTR + c4 * 4) = t;
  }
  __syncthreads();

  // ---- MFMA over this wave's 128-K chunk ----
  f32x4 acc = {0.f, 0.f, 0.f, 0.f};
#pragma unroll
  for (int kk = 0; kk < 4; ++kk) {
    bf16x8 b = *(const bf16x8*)(Wt + l15 * WSTR + wv * 128 + kk * 32 + quad * 8);
    acc = mfma16(af[kk], b, acc);
  }

  // ---- reduce 4 waves, write 16x16 partial ----
  *(f32x4*)(&red[wv][lane][0]) = acc;
  __syncthreads();
  if (wv == 0) {
#pragma unroll
    for (int r = 0; r < 4; ++r) {
      float v = red[0][lane][r] + red[1][lane][r] + red[2][lane][r] + red[3][lane][r];
      partial[((size_t)(kq * NT + nt) * 16 + (quad * 4 + r)) * 16 + l15] = v;
    }
  }
}

// ---------------- qkv finish: 8-way reduce + RoPE -> Qfrag/Kfrag bf16, Vnew bf16 ----------------
__device__ __forceinline__ float sum_part(const float* p, int NT, int n, int m) {
  float s = 0.f;
#pragma unroll
  for (int q = 0; q < KS; ++q)
    s += p[((size_t)(q * NT + (n >> 4)) * 16 + m) * 16 + (n & 15)];
  return s;
}

__global__ __launch_bounds__(256) void qkv_finish_kernel(const float* __restrict__ pq,
                                                         bf16* __restrict__ Qf,
                                                         bf16* __restrict__ Kf,
                                                         bf16* __restrict__ Vn) {
  int id = blockIdx.x * 256 + threadIdx.x;   // 57344 total
  if (id < 32768) {           // Q: 32 heads x 16 m x 64 pairs
    int qh = id >> 10, m = (id >> 6) & 15, j = id & 63;
    float e = sum_part(pq, 384, qh * 128 + j, m);
    float o = sum_part(pq, 384, qh * 128 + 64 + j, m);
    float sn, co;
    __sincosf((float)m * (float)j * (1.0f / 64.0f), &sn, &co);
    Qf[qh * 2048 + fmidx(j, m)] = (bf16)((e * co - o * sn) * SCALE);
    Qf[qh * 2048 + fmidx(j + 64, m)] = (bf16)((e * sn + o * co) * SCALE);
  } else if (id < 40960) {    // K: 8 heads x 16 m x 64 pairs
    int v = id - 32768;
    int kvh = v >> 10, m = (v >> 6) & 15, j = v & 63;
    float e = sum_part(pq, 384, 4096 + kvh * 128 + j, m);
    float o = sum_part(pq, 384, 4096 + kvh * 128 + 64 + j, m);
    float sn, co;
    __sincosf((float)m * (float)j * (1.0f / 64.0f), &sn, &co);
    Kf[kvh * 2048 + fmidx(j, m)] = (bf16)(e * co - o * sn);
    Kf[kvh * 2048 + fmidx(j + 64, m)] = (bf16)(e * sn + o * co);
  } else if (id < 57344) {    // V: 8 heads x 16 m x 128 d
    int v = id - 40960;
    int kvh = v >> 11, m = (v >> 7) & 15, d = v & 127;
    Vn[kvh * 2048 + m * 128 + d] = (bf16)sum_part(pq, 384, 5120 + kvh * 128 + d, m);
  }
}

// ---------------- attention partials ----------------
template <bool NEW>
__device__ void attn_body(int kvh, int c,
                          const float* __restrict__ ck, const float* __restrict__ cv,
                          const bf16* __restrict__ Qf, const bf16* __restrict__ Kf,
                          const bf16* __restrict__ Vn,
                          bf16* __restrict__ Opart, float* __restrict__ ml,
                          bf16* Kt, bf16* Vt, bf16* Pl) {
  int tid = threadIdx.x, lane = tid & 63, wv = tid >> 6;
  int l15 = lane & 15, quad = lane >> 4;
  int qh = kvh * 4 + wv;
  int cs = c * ACH;

  // ---- Q fragments hoisted: global loads issue before staging stores, so their
  //      latency hides under the K/V staging; consumed only after __syncthreads.
  bf16x8 af[4];
#pragma unroll
  for (int kk = 0; kk < 4; ++kk)
    af[kk] = *(const bf16x8*)(Qf + qh * 2048 + ((kk * 4 + quad) * 16 + l15) * 8);

  // ---- staging ----
  if (!NEW) {
    // K tile 64 x 128 fp32, coalesced float4 -> Kt[key][d] stride 136
    {
      int kr = tid >> 5;           // +8 per iteration
      int kc4 = tid & 31;
      f32x4 kst[8];
#pragma unroll
      for (int it = 0; it < 8; ++it)
        kst[it] = *(const f32x4*)(ck + ((size_t)(kvh * MAXLEN + cs + it * 8 + kr)) * HD + kc4 * 4);
      // V tile 64 x 128 fp32 -> Vt[d][key] stride 72 (transposed)
      int key = tid & 63, dg = tid >> 6;  // dg*32 .. +31
      f32x4 vst[8];
#pragma unroll
      for (int q4 = 0; q4 < 8; ++q4)
        vst[q4] = *(const f32x4*)(cv + ((size_t)(kvh * MAXLEN + cs + key)) * HD + dg * 32 + q4 * 4);
#pragma unroll
      for (int it = 0; it < 8; ++it) {
        bf16x4 t;
        t[0] = (bf16)kst[it][0]; t[1] = (bf16)kst[it][1];
        t[2] = (bf16)kst[it][2]; t[3] = (bf16)kst[it][3];
        *(bf16x4*)(Kt + (it * 8 + kr) * 136 + kc4 * 4) = t;
      }
#pragma unroll
      for (int q4 = 0; q4 < 8; ++q4)
#pragma unroll
        for (int i = 0; i < 4; ++i)
          Vt[(dg * 32 + q4 * 4 + i) * 72 + key] = (bf16)vst[q4][i];
    }
  } else {
    // V-new: 16 keys x 128 d bf16 -> Vt transposed, zero pad keys 16..31
    int key = tid >> 4, dg8 = tid & 15;
    bf16x8 v = *(const bf16x8*)(Vn + kvh * 2048 + key * 128 + dg8 * 8);
#pragma unroll
    for (int i = 0; i < 8; ++i) {
      Vt[(dg8 * 8 + i) * 72 + key] = v[i];
      Vt[(dg8 * 8 + i) * 72 + 16 + key] = (bf16)0.f;
    }
  }
  __syncthreads();

  // ---- scores ----
  constexpr int NT = NEW ? 1 : 4;
  f32x4 sc[NT];
  if (!NEW) {
#pragma unroll
    for (int nt = 0; nt < NT; ++nt) {
      f32x4 acc = {0.f, 0.f, 0.f, 0.f};
#pragma unroll
      for (int kk = 0; kk < 4; ++kk) {
        bf16x8 b = *(const bf16x8*)(Kt + (nt * 16 + l15) * 136 + kk * 32 + quad * 8);
        acc = mfma16(af[kk], b, acc);
      }
      sc[nt] = acc;
    }
  } else {
    f32x4 acc = {0.f, 0.f, 0.f, 0.f};
#pragma unroll
    for (int kk = 0; kk < 4; ++kk) {
      bf16x8 b = *(const bf16x8*)(Kf + kvh * 2048 + ((kk * 4 + quad) * 16 + l15) * 8);
      acc = mfma16(af[kk], b, acc);
    }
#pragma unroll
    for (int r = 0; r < 4; ++r)
      if (l15 > quad * 4 + r) acc[r] = NEGBIG;
    sc[0] = acc;
  }

  // ---- per-chunk softmax ----
  float mx[4], sm[4];
#pragma unroll
  for (int r = 0; r < 4; ++r) {
    float v = sc[0][r];
#pragma unroll
    for (int nt = 1; nt < NT; ++nt) v = fmaxf(v, sc[nt][r]);
    v = fmaxf(v, __shfl_xor(v, 1));
    v = fmaxf(v, __shfl_xor(v, 2));
    v = fmaxf(v, __shfl_xor(v, 4));
    v = fmaxf(v, __shfl_xor(v, 8));
    mx[r] = v;
  }
#pragma unroll
  for (int nt = 0; nt < NT; ++nt)
#pragma unroll
    for (int r = 0; r < 4; ++r) sc[nt][r] = __expf(sc[nt][r] - mx[r]);
#pragma unroll
  for (int r = 0; r < 4; ++r) {
    float v = 0.f;
#pragma unroll
    for (int nt = 0; nt < NT; ++nt) v += sc[nt][r];
    v += __shfl_xor(v, 1);
    v += __shfl_xor(v, 2);
    v += __shfl_xor(v, 4);
    v += __shfl_xor(v, 8);
    sm[r] = v;
  }

  // ---- P -> LDS (C- to A-layout), stride 72 ----
  bf16* Pw = Pl + wv * 16 * 72;
#pragma unroll
  for (int nt = 0; nt < NT; ++nt)
#pragma unroll
    for (int r = 0; r < 4; ++r)
      Pw[(quad * 4 + r) * 72 + nt * 16 + l15] = (bf16)sc[nt][r];
  if (NEW) {
#pragma unroll
    for (int r = 0; r < 4; ++r)
      Pw[(quad * 4 + r) * 72 + 16 + l15] = (bf16)0.f;
  }
  __syncthreads();   // cross-lane LDS RAW

  // ---- O = P V ----
  constexpr int KI = NEW ? 1 : 2;
  int rowblk = ((kvh * NCH + c) * 4 + wv) * 16;
  bf16* ob = Opart + (size_t)rowblk * 128;
#pragma unroll
  for (int nt2 = 0; nt2 < 8; ++nt2) {
    f32x4 acc = {0.f, 0.f, 0.f, 0.f};
#pragma unroll
    for (int kk = 0; kk < KI; ++kk) {
      bf16x8 a = *(const bf16x8*)(Pw + l15 * 72 + kk * 32 + quad * 8);
      bf16x8 b = *(const bf16x8*)(Vt + (nt2 * 16 + l15) * 72 + kk * 32 + quad * 8);
      acc = mfma16(a, b, acc);
    }
#pragma unroll
    for (int r = 0; r < 4; ++r)
      ob[(quad * 4 + r) * 128 + nt2 * 16 + l15] = (bf16)acc[r];
  }
  if (l15 == 0) {
#pragma unroll
    for (int r = 0; r < 4; ++r) {
      ml[(size_t)(rowblk + quad * 4 + r) * 2] = mx[r];
      ml[(size_t)(rowblk + quad * 4 + r) * 2 + 1] = sm[r];
    }
  }
}

__global__ __launch_bounds__(256) void attn_kernel(const float* __restrict__ ck,
                                                   const float* __restrict__ cv,
                                                   const bf16* __restrict__ Qf,
                                                   const bf16* __restrict__ Kf,
                                                   const bf16* __restrict__ Vn,
                                                   bf16* __restrict__ Opart,
                                                   float* __restrict__ ml) {
  __shared__ __align__(16) bf16 KtL[64 * 136];
  __shared__ __align__(16) bf16 VtL[128 * 72];
  __shared__ __align__(16) bf16 PL[4 * 16 * 72];
  int c = blockIdx.x % NCH;
  int kvh = blockIdx.x / NCH;
  if (c == NCH - 1)
    attn_body<true>(kvh, c, ck, cv, Qf, Kf, Vn, Opart, ml, KtL, VtL, PL);
  else
    attn_body<false>(kvh, c, ck, cv, Qf, Kf, Vn, Opart, ml, KtL, VtL, PL);
}

// ---------------- combine: 512 blocks, one (qh, srow) per block ----------------
// NOTE: this body requires grid = 512 (qh = blockIdx.x >> 4). R3 failed because it
// was launched at 128; launch-config and body must be changed together.
__global__ __launch_bounds__(256) void combine_kernel(const bf16* __restrict__ Opart,
                                                      const float* __restrict__ ml,
                                                      bf16* __restrict__ attfm) {
  int tid = threadIdx.x, lane = tid & 63, wv = tid >> 6;
  int qh = blockIdx.x >> 4, srow = blockIdx.x & 15;
  int kvh = qh >> 2, lw = qh & 3;
  size_t rowblk0 = ((size_t)(kvh * NCH) * 4 + lw) * 16 + srow;

  // pass 1: wave-local max over its chunks (4-way split across waves)
  float mw = NEGBIG;
#pragma unroll 4
  for (int c = wv; c < NCH; c += 4)
    mw = fmaxf(mw, ml[(rowblk0 + (size_t)c * 64) * 2]);

  // pass 2: weighted accumulate (lane owns dims lane and lane+64)
  float a0 = 0.f, a1 = 0.f, Lw = 0.f;
#pragma unroll 2
  for (int c = wv; c < NCH; c += 4) {
    const float* mlc = ml + (rowblk0 + (size_t)c * 64) * 2;
    float wc = __expf(mlc[0] - mw);
    Lw += wc * mlc[1];
    const bf16* oc = Opart + (rowblk0 + (size_t)c * 64) * 128;
    a0 += wc * (float)oc[lane];
    a1 += wc * (float)oc[64 + lane];
  }

  __shared__ float sm_m[4], sm_l[4];
  __shared__ float sm_a[4][128];
  if (lane == 0) { sm_m[wv] = mw; sm_l[wv] = Lw; }
  sm_a[wv][lane] = a0;
  sm_a[wv][64 + lane] = a1;
  __syncthreads();

  if (wv == 0) {
    float M = fmaxf(fmaxf(sm_m[0], sm_m[1]), fmaxf(sm_m[2], sm_m[3]));
    float s0 = __expf(sm_m[0] - M), s1 = __expf(sm_m[1] - M);
    float s2 = __expf(sm_m[2] - M), s3 = __expf(sm_m[3] - M);
    float L = s0 * sm_l[0] + s1 * sm_l[1] + s2 * sm_l[2] + s3 * sm_l[3];
    float inv = 1.f / L;
    float A0 = s0 * sm_a[0][lane] + s1 * sm_a[1][lane] + s2 * sm_a[2][lane] + s3 * sm_a[3][lane];
    float A1 = s0 * sm_a[0][64 + lane] + s1 * sm_a[1][64 + lane] +
               s2 * sm_a[2][64 + lane] + s3 * sm_a[3][64 + lane];
    int k1 = qh * 128 + lane, k2 = k1 + 64;
    attfm[fmidx(k1, srow)] = (bf16)(A0 * inv);
    attfm[fmidx(k2, srow)] = (bf16)(A1 * inv);
  }
}

// ---------------- proj reduce: sum 8 partials -> fp32 out ----------------
__global__ __launch_bounds__(256) void proj_reduce_kernel(const float* __restrict__ pp,
                                                          float* __restrict__ out) {
  int flat = blockIdx.x * 256 + threadIdx.x;  // 16384 float4s
  int m = flat >> 10, n = (flat & 1023) * 4;
  f32x4 s = {0.f, 0.f, 0.f, 0.f};
#pragma unroll
  for (int q = 0; q < KS; ++q)
    s += *(const f32x4*)(pp + ((size_t)(q * 256 + (n >> 4)) * 16 + m) * 16 + (n & 15));
  *(f32x4*)(out + (size_t)m * HID + n) = s;
}

extern "C" void kernel_launch(void* const* d_in, const int* in_sizes, int n_in,
                              void* d_out, int out_size, void* d_ws, size_t ws_size,
                              hipStream_t stream) {
  const float* x       = (const float*)d_in[0];
  const float* w_qkv   = (const float*)d_in[1];
  const float* w_out   = (const float*)d_in[2];
  const float* cache_k = (const float*)d_in[3];
  const float* cache_v = (const float*)d_in[4];
  float* out = (float*)d_out;

  char* p = (char*)d_ws;
  bf16*  Xfrag = (bf16*)p;               p += (size_t)16 * HID * 2;            // 128 KB
  float* partQ = (float*)p;              p += (size_t)KS * 384 * 256 * 4;      // 3 MB
  bf16*  Qf    = (bf16*)p;               p += (size_t)NQH * 2048 * 2;          // 128 KB
  bf16*  Kf    = (bf16*)p;               p += (size_t)NKVH * 2048 * 2;         // 32 KB
  bf16*  Vn    = (bf16*)p;               p += (size_t)NKVH * 2048 * 2;         // 32 KB
  bf16*  Opart = (bf16*)p;               p += (size_t)NKVH * NCH * 4 * 16 * 128 * 2;  // 8.5 MB
  float* ml    = (float*)p;              p += (size_t)NKVH * NCH * 4 * 16 * 2 * 4;    // 266 KB
  bf16*  attfm = (bf16*)p;               p += (size_t)16 * HID * 2;            // 128 KB
  float* partP = (float*)p;              p += (size_t)KS * 256 * 256 * 4;      // 2 MB

  hipLaunchKernelGGL(xprep_kernel, dim3(32), dim3(256), 0, stream, x, Xfrag);
  hipLaunchKernelGGL((gemm16_kernel<384>), dim3(384 * KS), dim3(256), 0, stream, Xfrag, w_qkv, partQ);
  hipLaunchKernelGGL(qkv_finish_kernel, dim3(224), dim3(256), 0, stream, partQ, Qf, Kf, Vn);
  hipLaunchKernelGGL(attn_kernel, dim3(NKVH * NCH), dim3(256), 0, stream,
                     cache_k, cache_v, Qf, Kf, Vn, Opart, ml);
  hipLaunchKernelGGL(combine_kernel, dim3(512), dim3(256), 0, stream, Opart, ml, attfm);
  hipLaunchKernelGGL((gemm16_kernel<256>), dim3(256 * KS), dim3(256), 0, stream, attfm, w_out, partP);
  hipLaunchKernelGGL(proj_reduce_kernel, dim3(64), dim3(256), 0, stream, partP, out);
}

// Round 5
// 255.311 us; speedup vs baseline: 2.3437x; 1.0088x over previous
//
#include <hip/hip_runtime.h>
#include <hip/hip_bf16.h>

typedef __bf16 bf16;
typedef __bf16 bf16x4 __attribute__((ext_vector_type(4)));
typedef __bf16 bf16x8 __attribute__((ext_vector_type(8)));
typedef float f32x4 __attribute__((ext_vector_type(4)));

#define HID 4096
#define QKVN 6144
#define NQH 32
#define NKVH 8
#define HD 128
#define MAXLEN 8192
#define PAST 4096
#define SQ 16
#define SCALE 0.08838834764831845f
#define NEGBIG (-30000.0f)

// GEMM K-split config
#define KS 8          // K splits (blocks per N-tile)
#define KPB 512       // K elements per block
#define WSTR 520      // LDS row stride (elements) for W tile
// attention chunking
#define ACH 64        // keys per past chunk
#define NCH 65        // 64 past chunks + 1 new chunk

__device__ __forceinline__ f32x4 mfma16(bf16x8 a, bf16x8 b, f32x4 c) {
  return __builtin_amdgcn_mfma_f32_16x16x32_bf16(a, b, c, 0, 0, 0);
}

__device__ __forceinline__ bf16x8 load8f(const float* p) {
  const f32x4* q = (const f32x4*)p;
  f32x4 a = q[0], b = q[1];
  bf16x8 r;
  r[0] = (bf16)a[0]; r[1] = (bf16)a[1]; r[2] = (bf16)a[2]; r[3] = (bf16)a[3];
  r[4] = (bf16)b[0]; r[5] = (bf16)b[1]; r[6] = (bf16)b[2]; r[7] = (bf16)b[3];
  return r;
}

__device__ __forceinline__ int fmidx(int k, int m) {
  return ((k >> 3) * 16 + m) * 8 + (k & 7);
}

// ---------------- GEMM: C16[m][n] over one 512-K slice ----------------
// A source: AF32 ? fp32 row-major [16][HID] (x, L2-resident; R1-proven mapping)
//                 : fragment-major bf16 (attfm; R4-proven mapping).
// Epilogue: ATOMIC ? fp32 atomicAdd into out[m][OSTR] (target pre-zeroed)
//                  : partial store (reduced later by qkv_finish's sum_part).
// W staging via LDS kept from R0 (removing it regressed in R1).
template <int NT, bool AF32, bool ATOMIC, int OSTR>
__global__ __launch_bounds__(256) void gemm16_kernel(const void* __restrict__ aptr,
                                                     const float* __restrict__ w,
                                                     float* __restrict__ outp) {
  int tid = threadIdx.x, lane = tid & 63, wv = tid >> 6;
  int l15 = lane & 15, quad = lane >> 4;
  int nt = blockIdx.x % NT, kq = blockIdx.x / NT;

  __shared__ __align__(16) bf16 Wt[16 * WSTR];
  __shared__ __align__(16) float red[4][64][4];

  // ---- stage W tile 16 x 512 fp32 -> bf16 LDS, fully coalesced ----
  const float* wb = w + (size_t)(nt * 16) * HID + kq * KPB;
  int r2 = tid >> 7;        // 0..1 (2 rows per iteration)
  int c4 = tid & 127;       // float4 column
  f32x4 stg[8];
#pragma unroll
  for (int it = 0; it < 8; ++it)
    stg[it] = *(const f32x4*)(wb + (size_t)(it * 2 + r2) * HID + c4 * 4);

  // ---- A fragments (independent of LDS stores; latency hides under staging) ----
  bf16x8 af[4];
  if constexpr (AF32) {
    const float* ab = (const float*)aptr + (size_t)l15 * HID + kq * KPB + wv * 128 + quad * 8;
#pragma unroll
    for (int kk = 0; kk < 4; ++kk)
      af[kk] = load8f(ab + kk * 32);
  } else {
    int obase = kq * 64 + wv * 16;   // octet base (K = kq*512 + wv*128)
    const bf16* ab = (const bf16*)aptr;
#pragma unroll
    for (int kk = 0; kk < 4; ++kk)
      af[kk] = *(const bf16x8*)(ab + (size_t)((obase + kk * 4 + quad) * 16 + l15) * 8);
  }

#pragma unroll
  for (int it = 0; it < 8; ++it) {
    bf16x4 t;
    t[0] = (bf16)stg[it][0]; t[1] = (bf16)stg[it][1];
    t[2] = (bf16)stg[it][2]; t[3] = (bf16)stg[it][3];
    *(bf16x4*)(Wt + (it * 2 + r2) * WSTR + c4 * 4) = t;
  }
  __syncthreads();

  // ---- MFMA over this wave's 128-K chunk ----
  f32x4 acc = {0.f, 0.f, 0.f, 0.f};
#pragma unroll
  for (int kk = 0; kk < 4; ++kk) {
    bf16x8 b = *(const bf16x8*)(Wt + l15 * WSTR + wv * 128 + kk * 32 + quad * 8);
    acc = mfma16(af[kk], b, acc);
  }

  // ---- reduce 4 waves ----
  *(f32x4*)(&red[wv][lane][0]) = acc;
  __syncthreads();
  if (wv == 0) {
#pragma unroll
    for (int r = 0; r < 4; ++r) {
      float v = red[0][lane][r] + red[1][lane][r] + red[2][lane][r] + red[3][lane][r];
      if constexpr (ATOMIC) {
        atomicAdd(outp + (size_t)(quad * 4 + r) * OSTR + nt * 16 + l15, v);
      } else {
        outp[((size_t)(kq * NT + nt) * 16 + (quad * 4 + r)) * 16 + l15] = v;
      }
    }
  }
}

// ---------------- qkv finish: 8-way reduce + RoPE -> Qfrag/Kfrag bf16, Vnew bf16 ----------------
__device__ __forceinline__ float sum_part(const float* p, int NT, int n, int m) {
  float s = 0.f;
#pragma unroll
  for (int q = 0; q < KS; ++q)
    s += p[((size_t)(q * NT + (n >> 4)) * 16 + m) * 16 + (n & 15)];
  return s;
}

__global__ __launch_bounds__(256) void qkv_finish_kernel(const float* __restrict__ pq,
                                                         bf16* __restrict__ Qf,
                                                         bf16* __restrict__ Kf,
                                                         bf16* __restrict__ Vn) {
  int id = blockIdx.x * 256 + threadIdx.x;   // 57344 total
  if (id < 32768) {           // Q: 32 heads x 16 m x 64 pairs
    int qh = id >> 10, m = (id >> 6) & 15, j = id & 63;
    float e = sum_part(pq, 384, qh * 128 + j, m);
    float o = sum_part(pq, 384, qh * 128 + 64 + j, m);
    float sn, co;
    __sincosf((float)m * (float)j * (1.0f / 64.0f), &sn, &co);
    Qf[qh * 2048 + fmidx(j, m)] = (bf16)((e * co - o * sn) * SCALE);
    Qf[qh * 2048 + fmidx(j + 64, m)] = (bf16)((e * sn + o * co) * SCALE);
  } else if (id < 40960) {    // K: 8 heads x 16 m x 64 pairs
    int v = id - 32768;
    int kvh = v >> 10, m = (v >> 6) & 15, j = v & 63;
    float e = sum_part(pq, 384, 4096 + kvh * 128 + j, m);
    float o = sum_part(pq, 384, 4096 + kvh * 128 + 64 + j, m);
    float sn, co;
    __sincosf((float)m * (float)j * (1.0f / 64.0f), &sn, &co);
    Kf[kvh * 2048 + fmidx(j, m)] = (bf16)(e * co - o * sn);
    Kf[kvh * 2048 + fmidx(j + 64, m)] = (bf16)(e * sn + o * co);
  } else if (id < 57344) {    // V: 8 heads x 16 m x 128 d
    int v = id - 40960;
    int kvh = v >> 11, m = (v >> 7) & 15, d = v & 127;
    Vn[kvh * 2048 + m * 128 + d] = (bf16)sum_part(pq, 384, 5120 + kvh * 128 + d, m);
  }
}

// ---------------- attention partials ----------------
template <bool NEW>
__device__ void attn_body(int kvh, int c,
                          const float* __restrict__ ck, const float* __restrict__ cv,
                          const bf16* __restrict__ Qf, const bf16* __restrict__ Kf,
                          const bf16* __restrict__ Vn,
                          bf16* __restrict__ Opart, float* __restrict__ ml,
                          bf16* Kt, bf16* Vt, bf16* Pl) {
  int tid = threadIdx.x, lane = tid & 63, wv = tid >> 6;
  int l15 = lane & 15, quad = lane >> 4;
  int qh = kvh * 4 + wv;
  int cs = c * ACH;

  // ---- Q fragments hoisted: latency hides under K/V staging ----
  bf16x8 af[4];
#pragma unroll
  for (int kk = 0; kk < 4; ++kk)
    af[kk] = *(const bf16x8*)(Qf + qh * 2048 + ((kk * 4 + quad) * 16 + l15) * 8);

  // ---- staging ----
  if (!NEW) {
    // K tile 64 x 128 fp32, coalesced float4 -> Kt[key][d] stride 136
    {
      int kr = tid >> 5;           // +8 per iteration
      int kc4 = tid & 31;
      f32x4 kst[8];
#pragma unroll
      for (int it = 0; it < 8; ++it)
        kst[it] = *(const f32x4*)(ck + ((size_t)(kvh * MAXLEN + cs + it * 8 + kr)) * HD + kc4 * 4);
      // V tile 64 x 128 fp32 -> Vt[d][key] stride 72 (transposed)
      int key = tid & 63, dg = tid >> 6;  // dg*32 .. +31
      f32x4 vst[8];
#pragma unroll
      for (int q4 = 0; q4 < 8; ++q4)
        vst[q4] = *(const f32x4*)(cv + ((size_t)(kvh * MAXLEN + cs + key)) * HD + dg * 32 + q4 * 4);
#pragma unroll
      for (int it = 0; it < 8; ++it) {
        bf16x4 t;
        t[0] = (bf16)kst[it][0]; t[1] = (bf16)kst[it][1];
        t[2] = (bf16)kst[it][2]; t[3] = (bf16)kst[it][3];
        *(bf16x4*)(Kt + (it * 8 + kr) * 136 + kc4 * 4) = t;
      }
#pragma unroll
      for (int q4 = 0; q4 < 8; ++q4)
#pragma unroll
        for (int i = 0; i < 4; ++i)
          Vt[(dg * 32 + q4 * 4 + i) * 72 + key] = (bf16)vst[q4][i];
    }
  } else {
    // V-new: 16 keys x 128 d bf16 -> Vt transposed, zero pad keys 16..31
    int key = tid >> 4, dg8 = tid & 15;
    bf16x8 v = *(const bf16x8*)(Vn + kvh * 2048 + key * 128 + dg8 * 8);
#pragma unroll
    for (int i = 0; i < 8; ++i) {
      Vt[(dg8 * 8 + i) * 72 + key] = v[i];
      Vt[(dg8 * 8 + i) * 72 + 16 + key] = (bf16)0.f;
    }
  }
  __syncthreads();

  // ---- scores ----
  constexpr int NT = NEW ? 1 : 4;
  f32x4 sc[NT];
  if (!NEW) {
#pragma unroll
    for (int nt = 0; nt < NT; ++nt) {
      f32x4 acc = {0.f, 0.f, 0.f, 0.f};
#pragma unroll
      for (int kk = 0; kk < 4; ++kk) {
        bf16x8 b = *(const bf16x8*)(Kt + (nt * 16 + l15) * 136 + kk * 32 + quad * 8);
        acc = mfma16(af[kk], b, acc);
      }
      sc[nt] = acc;
    }
  } else {
    f32x4 acc = {0.f, 0.f, 0.f, 0.f};
#pragma unroll
    for (int kk = 0; kk < 4; ++kk) {
      bf16x8 b = *(const bf16x8*)(Kf + kvh * 2048 + ((kk * 4 + quad) * 16 + l15) * 8);
      acc = mfma16(af[kk], b, acc);
    }
#pragma unroll
    for (int r = 0; r < 4; ++r)
      if (l15 > quad * 4 + r) acc[r] = NEGBIG;
    sc[0] = acc;
  }

  // ---- per-chunk softmax ----
  float mx[4], sm[4];
#pragma unroll
  for (int r = 0; r < 4; ++r) {
    float v = sc[0][r];
#pragma unroll
    for (int nt = 1; nt < NT; ++nt) v = fmaxf(v, sc[nt][r]);
    v = fmaxf(v, __shfl_xor(v, 1));
    v = fmaxf(v, __shfl_xor(v, 2));
    v = fmaxf(v, __shfl_xor(v, 4));
    v = fmaxf(v, __shfl_xor(v, 8));
    mx[r] = v;
  }
#pragma unroll
  for (int nt = 0; nt < NT; ++nt)
#pragma unroll
    for (int r = 0; r < 4; ++r) sc[nt][r] = __expf(sc[nt][r] - mx[r]);
#pragma unroll
  for (int r = 0; r < 4; ++r) {
    float v = 0.f;
#pragma unroll
    for (int nt = 0; nt < NT; ++nt) v += sc[nt][r];
    v += __shfl_xor(v, 1);
    v += __shfl_xor(v, 2);
    v += __shfl_xor(v, 4);
    v += __shfl_xor(v, 8);
    sm[r] = v;
  }

  // ---- P -> LDS (C- to A-layout), stride 72 ----
  bf16* Pw = Pl + wv * 16 * 72;
#pragma unroll
  for (int nt = 0; nt < NT; ++nt)
#pragma unroll
    for (int r = 0; r < 4; ++r)
      Pw[(quad * 4 + r) * 72 + nt * 16 + l15] = (bf16)sc[nt][r];
  if (NEW) {
#pragma unroll
    for (int r = 0; r < 4; ++r)
      Pw[(quad * 4 + r) * 72 + 16 + l15] = (bf16)0.f;
  }
  __syncthreads();   // cross-lane LDS RAW

  // ---- O = P V ----
  constexpr int KI = NEW ? 1 : 2;
  int rowblk = ((kvh * NCH + c) * 4 + wv) * 16;
  bf16* ob = Opart + (size_t)rowblk * 128;
#pragma unroll
  for (int nt2 = 0; nt2 < 8; ++nt2) {
    f32x4 acc = {0.f, 0.f, 0.f, 0.f};
#pragma unroll
    for (int kk = 0; kk < KI; ++kk) {
      bf16x8 a = *(const bf16x8*)(Pw + l15 * 72 + kk * 32 + quad * 8);
      bf16x8 b = *(const bf16x8*)(Vt + (nt2 * 16 + l15) * 72 + kk * 32 + quad * 8);
      acc = mfma16(a, b, acc);
    }
#pragma unroll
    for (int r = 0; r < 4; ++r)
      ob[(quad * 4 + r) * 128 + nt2 * 16 + l15] = (bf16)acc[r];
  }
  if (l15 == 0) {
#pragma unroll
    for (int r = 0; r < 4; ++r) {
      ml[(size_t)(rowblk + quad * 4 + r) * 2] = mx[r];
      ml[(size_t)(rowblk + quad * 4 + r) * 2 + 1] = sm[r];
    }
  }
}

__global__ __launch_bounds__(256) void attn_kernel(const float* __restrict__ ck,
                                                   const float* __restrict__ cv,
                                                   const bf16* __restrict__ Qf,
                                                   const bf16* __restrict__ Kf,
                                                   const bf16* __restrict__ Vn,
                                                   bf16* __restrict__ Opart,
                                                   float* __restrict__ ml) {
  __shared__ __align__(16) bf16 KtL[64 * 136];
  __shared__ __align__(16) bf16 VtL[128 * 72];
  __shared__ __align__(16) bf16 PL[4 * 16 * 72];
  int c = blockIdx.x % NCH;
  int kvh = blockIdx.x / NCH;
  if (c == NCH - 1)
    attn_body<true>(kvh, c, ck, cv, Qf, Kf, Vn, Opart, ml, KtL, VtL, PL);
  else
    attn_body<false>(kvh, c, ck, cv, Qf, Kf, Vn, Opart, ml, KtL, VtL, PL);
}

// ---------------- combine: 512 blocks, one (qh, srow) per block ----------------
// GRID MUST BE 512 (qh = blockIdx.x >> 4). Also zeroes `out` (gemm2's atomic target).
__global__ __launch_bounds__(256) void combine_kernel(const bf16* __restrict__ Opart,
                                                      const float* __restrict__ ml,
                                                      bf16* __restrict__ attfm,
                                                      float* __restrict__ out) {
  int tid = threadIdx.x, lane = tid & 63, wv = tid >> 6;
  int qh = blockIdx.x >> 4, srow = blockIdx.x & 15;
  int kvh = qh >> 2, lw = qh & 3;
  size_t rowblk0 = ((size_t)(kvh * NCH) * 4 + lw) * 16 + srow;

  // zero out[16][4096] fp32: 512 blocks x 32 f32x4 = 16384 (R1-proven)
  if (tid < 32) {
    f32x4 z = {0.f, 0.f, 0.f, 0.f};
    *(f32x4*)(out + (size_t)(blockIdx.x * 32 + tid) * 4) = z;
  }

  // pass 1: wave-local max over its chunks (4-way split across waves)
  float mw = NEGBIG;
#pragma unroll 4
  for (int c = wv; c < NCH; c += 4)
    mw = fmaxf(mw, ml[(rowblk0 + (size_t)c * 64) * 2]);

  // pass 2: weighted accumulate (lane owns dims lane and lane+64)
  float a0 = 0.f, a1 = 0.f, Lw = 0.f;
#pragma unroll 2
  for (int c = wv; c < NCH; c += 4) {
    const float* mlc = ml + (rowblk0 + (size_t)c * 64) * 2;
    float wc = __expf(mlc[0] - mw);
    Lw += wc * mlc[1];
    const bf16* oc = Opart + (rowblk0 + (size_t)c * 64) * 128;
    a0 += wc * (float)oc[lane];
    a1 += wc * (float)oc[64 + lane];
  }

  __shared__ float sm_m[4], sm_l[4];
  __shared__ float sm_a[4][128];
  if (lane == 0) { sm_m[wv] = mw; sm_l[wv] = Lw; }
  sm_a[wv][lane] = a0;
  sm_a[wv][64 + lane] = a1;
  __syncthreads();

  if (wv == 0) {
    float M = fmaxf(fmaxf(sm_m[0], sm_m[1]), fmaxf(sm_m[2], sm_m[3]));
    float s0 = __expf(sm_m[0] - M), s1 = __expf(sm_m[1] - M);
    float s2 = __expf(sm_m[2] - M), s3 = __expf(sm_m[3] - M);
    float L = s0 * sm_l[0] + s1 * sm_l[1] + s2 * sm_l[2] + s3 * sm_l[3];
    float inv = 1.f / L;
    float A0 = s0 * sm_a[0][lane] + s1 * sm_a[1][lane] + s2 * sm_a[2][lane] + s3 * sm_a[3][lane];
    float A1 = s0 * sm_a[0][64 + lane] + s1 * sm_a[1][64 + lane] +
               s2 * sm_a[2][64 + lane] + s3 * sm_a[3][64 + lane];
    int k1 = qh * 128 + lane, k2 = k1 + 64;
    attfm[fmidx(k1, srow)] = (bf16)(A0 * inv);
    attfm[fmidx(k2, srow)] = (bf16)(A1 * inv);
  }
}

extern "C" void kernel_launch(void* const* d_in, const int* in_sizes, int n_in,
                              void* d_out, int out_size, void* d_ws, size_t ws_size,
                              hipStream_t stream) {
  const float* x       = (const float*)d_in[0];
  const float* w_qkv   = (const float*)d_in[1];
  const float* w_out   = (const float*)d_in[2];
  const float* cache_k = (const float*)d_in[3];
  const float* cache_v = (const float*)d_in[4];
  float* out = (float*)d_out;

  char* p = (char*)d_ws;
  float* partQ = (float*)p;              p += (size_t)KS * 384 * 256 * 4;      // 3 MB
  bf16*  Qf    = (bf16*)p;               p += (size_t)NQH * 2048 * 2;          // 128 KB
  bf16*  Kf    = (bf16*)p;               p += (size_t)NKVH * 2048 * 2;         // 32 KB
  bf16*  Vn    = (bf16*)p;               p += (size_t)NKVH * 2048 * 2;         // 32 KB
  bf16*  Opart = (bf16*)p;               p += (size_t)NKVH * NCH * 4 * 16 * 128 * 2;  // 8.5 MB
  float* ml    = (float*)p;              p += (size_t)NKVH * NCH * 4 * 16 * 2 * 4;    // 266 KB
  bf16*  attfm = (bf16*)p;               p += (size_t)16 * HID * 2;            // 128 KB

  // 5-kernel pipeline (was 7): xprep folded into gemm<384> (AF32 A-path),
  // proj_reduce folded into gemm<256> (atomic epilogue; `out` zeroed by combine).
  hipLaunchKernelGGL((gemm16_kernel<384, true, false, 0>), dim3(384 * KS), dim3(256), 0, stream,
                     (const void*)x, w_qkv, partQ);
  hipLaunchKernelGGL(qkv_finish_kernel, dim3(224), dim3(256), 0, stream, partQ, Qf, Kf, Vn);
  hipLaunchKernelGGL(attn_kernel, dim3(NKVH * NCH), dim3(256), 0, stream,
                     cache_k, cache_v, Qf, Kf, Vn, Opart, ml);
  hipLaunchKernelGGL(combine_kernel, dim3(512), dim3(256), 0, stream, Opart, ml, attfm, out);
  hipLaunchKernelGGL((gemm16_kernel<256, false, true, HID>), dim3(256 * KS), dim3(256), 0, stream,
                     (const void*)attfm, w_out, out);
}